// Round 4
// baseline (344.242 us; speedup 1.0000x reference)
//
#include <hip/hip_runtime.h>

#define NN 1024
#define DD 128

typedef __attribute__((ext_vector_type(8))) __bf16 bf16x8;
typedef __attribute__((ext_vector_type(4))) float f32x4;

__device__ __forceinline__ float us2f(unsigned short b) { return __uint_as_float(((unsigned)b) << 16); }
__device__ __forceinline__ unsigned short f2bf(float f) {
    unsigned x = __float_as_uint(f);
    return (unsigned short)((x + 0x7fffu + ((x >> 16) & 1u)) >> 16);   // RNE
}

struct SEdge { float hiT[128][68]; float hjT[128][68]; float wS[128]; float lred; };
struct SGate { float uS[4][DD]; float aS[4][DD]; float hS[4][DD]; float sred[2][4]; };
struct SAgg  { float red[4][64][4]; };
union SU { SEdge edge; SGate gate; SAgg agg; float hS[4][DD]; };

// monotonic-counter grid barrier; all 256 blocks are co-resident (1 block/CU).
__device__ __forceinline__ void gridbar(unsigned* bar, unsigned target, int tid) {
    __syncthreads();
    if (tid == 0) {
        __threadfence();   // release: drain this block's stores to L2
        __hip_atomic_fetch_add(bar, 1u, __ATOMIC_RELEASE, __HIP_MEMORY_SCOPE_AGENT);
        while (__hip_atomic_load(bar, __ATOMIC_ACQUIRE, __HIP_MEMORY_SCOPE_AGENT) < target)
            __builtin_amdgcn_s_sleep(1);
        __threadfence();   // acquire: invalidate L1 before reading others' data
    }
    __syncthreads();
}

__global__ __launch_bounds__(256) void k_all(
    const float* __restrict__ nf, const float* __restrict__ adj, const float* __restrict__ ew,
    const float* __restrict__ We, const float* __restrict__ be,
    const float* __restrict__ Wu_all, const float* __restrict__ bu_all,
    const float* __restrict__ Wv_all, const float* __restrict__ bv_all,
    const float* __restrict__ Wg_all, const float* __restrict__ bg_all,
    const float* __restrict__ Wc1, const float* __restrict__ bc1,
    const float* __restrict__ Wc2, const float* __restrict__ bc2,
    float* __restrict__ hbuf, float* __restrict__ ubuf, float* __restrict__ aggbuf,
    unsigned short* __restrict__ vthbuf, unsigned short* __restrict__ vtlbuf,
    unsigned short* __restrict__ adjH, unsigned short* __restrict__ adjL,
    float* __restrict__ hi, float* __restrict__ hj,
    float* __restrict__ S1, float* __restrict__ S2,
    unsigned* __restrict__ ctrl,            // [0]=barrier, [1]=edge counter, [2]=lossAcc(float)
    float* __restrict__ outL)
{
    __shared__ SU sh;
    const int b = blockIdx.x, tid = threadIdx.x;
    unsigned* bar = ctrl;
    unsigned* edgeCnt = ctrl + 1;
    float* lossAcc = (float*)(ctrl + 2);
    const int d = tid & 127, half = tid >> 7;

    // ================= P0: adj split + embed + u/v layer 0 =================
    {
        // prep: this block's 4096-float chunk of adj -> bf16 hi/lo
#pragma unroll
        for (int i = 0; i < 4; ++i) {
            int idx = b * 4096 + i * 1024 + tid * 4;
            float4 a = *(const float4*)(adj + idx);
            ushort4 hv, lv;
            hv.x = f2bf(a.x); lv.x = f2bf(a.x - us2f(hv.x));
            hv.y = f2bf(a.y); lv.y = f2bf(a.y - us2f(hv.y));
            hv.z = f2bf(a.z); lv.z = f2bf(a.z - us2f(hv.z));
            hv.w = f2bf(a.w); lv.w = f2bf(a.w - us2f(hv.w));
            *(ushort4*)(adjH + idx) = hv;
            *(ushort4*)(adjL + idx) = lv;
        }
        // embed 4 rows
        int m0 = b * 4;
        if (half == 0) {
#pragma unroll
            for (int r = 0; r < 4; ++r) {
                float a = be[d];
#pragma unroll
                for (int k = 0; k < 3; ++k) a = fmaf(nf[(m0 + r) * 3 + k], We[k * DD + d], a);
                hbuf[(m0 + r) * DD + d] = a;
                sh.hS[r][d] = a;
            }
        }
        __syncthreads();
        const float* W = half ? Wv_all : Wu_all;
        float acc[4] = {0.f, 0.f, 0.f, 0.f};
#pragma unroll 4
        for (int k4 = 0; k4 < DD; k4 += 4) {
            f32x4 h0 = *(const f32x4*)&sh.hS[0][k4];
            f32x4 h1 = *(const f32x4*)&sh.hS[1][k4];
            f32x4 h2 = *(const f32x4*)&sh.hS[2][k4];
            f32x4 h3 = *(const f32x4*)&sh.hS[3][k4];
#pragma unroll
            for (int kk = 0; kk < 4; ++kk) {
                float w = W[(k4 + kk) * DD + d];
                acc[0] = fmaf(h0[kk], w, acc[0]);
                acc[1] = fmaf(h1[kk], w, acc[1]);
                acc[2] = fmaf(h2[kk], w, acc[2]);
                acc[3] = fmaf(h3[kk], w, acc[3]);
            }
        }
        if (half == 0) {
            float bb = bu_all[d];
#pragma unroll
            for (int r = 0; r < 4; ++r) ubuf[(m0 + r) * DD + d] = acc[r] + bb;
        } else {
            float bb = bv_all[d];
            float v0 = acc[0] + bb, v1 = acc[1] + bb, v2 = acc[2] + bb, v3 = acc[3] + bb;
            ushort4 hv, lv;
            hv.x = f2bf(v0); lv.x = f2bf(v0 - us2f(hv.x));
            hv.y = f2bf(v1); lv.y = f2bf(v1 - us2f(hv.y));
            hv.z = f2bf(v2); lv.z = f2bf(v2 - us2f(hv.z));
            hv.w = f2bf(v3); lv.w = f2bf(v3 - us2f(hv.w));
            *(ushort4*)(vthbuf + d * NN + m0) = hv;
            *(ushort4*)(vtlbuf + d * NN + m0) = lv;
        }
    }
    unsigned tgt = 256;
    gridbar(bar, tgt, tid); tgt += 256;

    // ================= 3 GCN layers =================
    for (int l = 0; l < 3; ++l) {
        const unsigned short* vth = vthbuf + l * (NN * DD);
        const unsigned short* vtl = vtlbuf + l * (NN * DD);
        float* aggl = aggbuf + l * (NN * DD);
        const float* ul = ubuf + l * (NN * DD);
        const float* hprev = hbuf + l * (NN * DD);

        // ---- agg phase: 2 (mt,nt) tiles per block, K split over wave pairs ----
        {
            int w = tid >> 6, lane = tid & 63;
            int mt = b & 63, np = b >> 6;
            int nt = np * 2 + (w >> 1);
            int kc = w & 1;
            int m = lane & 15, quad = lane >> 4;
            int k0 = kc * 512 + quad * 8;
            const unsigned short* ah = adjH + (size_t)(mt * 16 + m) * NN + k0;
            const unsigned short* al = adjL + (size_t)(mt * 16 + m) * NN + k0;
            const unsigned short* bh = vth + (size_t)(nt * 16 + m) * NN + k0;
            const unsigned short* bl = vtl + (size_t)(nt * 16 + m) * NN + k0;
            f32x4 acc = {0.f, 0.f, 0.f, 0.f};
#pragma unroll 4
            for (int kt = 0; kt < 16; ++kt) {
                bf16x8 aH = *(const bf16x8*)(ah + kt * 32);
                bf16x8 aL = *(const bf16x8*)(al + kt * 32);
                bf16x8 bH = *(const bf16x8*)(bh + kt * 32);
                bf16x8 bL = *(const bf16x8*)(bl + kt * 32);
                acc = __builtin_amdgcn_mfma_f32_16x16x32_bf16(aH, bH, acc, 0, 0, 0);
                acc = __builtin_amdgcn_mfma_f32_16x16x32_bf16(aH, bL, acc, 0, 0, 0);
                acc = __builtin_amdgcn_mfma_f32_16x16x32_bf16(aL, bH, acc, 0, 0, 0);
            }
            *(f32x4*)&sh.agg.red[w][lane][0] = acc;
            __syncthreads();
            if ((w & 1) == 0) {
                f32x4 s = *(const f32x4*)&sh.agg.red[w][lane][0];
                f32x4 t = *(const f32x4*)&sh.agg.red[w + 1][lane][0];
                int row0 = mt * 16 + quad * 4;
                int col = nt * 16 + m;
#pragma unroll
                for (int r = 0; r < 4; ++r) aggl[(row0 + r) * DD + col] = s[r] + t[r];
            }
        }
        gridbar(bar, tgt, tid); tgt += 256;

        // ---- gate phase (4 rows per block) ----
        {
            int m0 = b * 4;
            if (tid < 8) sh.gate.sred[tid >> 2][tid & 3] = 0.f;
#pragma unroll
            for (int e = tid; e < 512; e += 256) {
                int r = e >> 7, dd = e & 127;
                int idx = (m0 + r) * DD + dd;
                sh.gate.aS[r][dd] = aggl[idx];
                sh.gate.uS[r][dd] = ul[idx];
            }
            __syncthreads();
            const float* WA = Wg_all + l * (2 * DD * DD);
            const float* WB = WA + DD * DD;
            int r0 = half * 2;
            float acc[2] = {0.f, 0.f};
#pragma unroll 4
            for (int k4 = 0; k4 < DD; k4 += 4) {
                f32x4 u0 = *(const f32x4*)&sh.gate.uS[r0][k4];
                f32x4 u1 = *(const f32x4*)&sh.gate.uS[r0 + 1][k4];
                f32x4 a0 = *(const f32x4*)&sh.gate.aS[r0][k4];
                f32x4 a1 = *(const f32x4*)&sh.gate.aS[r0 + 1][k4];
#pragma unroll
                for (int kk = 0; kk < 4; ++kk) {
                    float wa = WA[(k4 + kk) * DD + d];
                    float wb = WB[(k4 + kk) * DD + d];
                    acc[0] = fmaf(u0[kk], wa, fmaf(a0[kk], wb, acc[0]));
                    acc[1] = fmaf(u1[kk], wa, fmaf(a1[kk], wb, acc[1]));
                }
            }
            float bgd = bg_all[l * DD + d];
#pragma unroll
            for (int rr = 0; rr < 2; ++rr) {
                int r = r0 + rr;
                float g = 1.f / (1.f + __expf(-(acc[rr] + bgd)));
                float nh = fmaf(g, sh.gate.aS[r][d], hprev[(m0 + r) * DD + d]);
                nh = nh > 0.f ? nh : 0.f;
                sh.gate.hS[r][d] = nh;
                if (l < 2) hbuf[(l + 1) * (NN * DD) + (m0 + r) * DD + d] = nh;
            }
            __syncthreads();
            if (l < 2) {
                // next-layer u/v GEMM
                const float* W = half ? (Wv_all + (l + 1) * (DD * DD)) : (Wu_all + (l + 1) * (DD * DD));
                float av[4] = {0.f, 0.f, 0.f, 0.f};
#pragma unroll 4
                for (int k4 = 0; k4 < DD; k4 += 4) {
                    f32x4 h0 = *(const f32x4*)&sh.gate.hS[0][k4];
                    f32x4 h1 = *(const f32x4*)&sh.gate.hS[1][k4];
                    f32x4 h2 = *(const f32x4*)&sh.gate.hS[2][k4];
                    f32x4 h3 = *(const f32x4*)&sh.gate.hS[3][k4];
#pragma unroll
                    for (int kk = 0; kk < 4; ++kk) {
                        float w = W[(k4 + kk) * DD + d];
                        av[0] = fmaf(h0[kk], w, av[0]);
                        av[1] = fmaf(h1[kk], w, av[1]);
                        av[2] = fmaf(h2[kk], w, av[2]);
                        av[3] = fmaf(h3[kk], w, av[3]);
                    }
                }
                if (half == 0) {
                    float bb = bu_all[(l + 1) * DD + d];
#pragma unroll
                    for (int r = 0; r < 4; ++r)
                        ubuf[(l + 1) * (NN * DD) + (m0 + r) * DD + d] = av[r] + bb;
                } else {
                    float bb = bv_all[(l + 1) * DD + d];
                    float v0 = av[0] + bb, v1 = av[1] + bb, v2 = av[2] + bb, v3 = av[3] + bb;
                    ushort4 hv, lv;
                    hv.x = f2bf(v0); lv.x = f2bf(v0 - us2f(hv.x));
                    hv.y = f2bf(v1); lv.y = f2bf(v1 - us2f(hv.y));
                    hv.z = f2bf(v2); lv.z = f2bf(v2 - us2f(hv.z));
                    hv.w = f2bf(v3); lv.w = f2bf(v3 - us2f(hv.w));
                    *(ushort4*)(vthbuf + (l + 1) * (NN * DD) + d * NN + m0) = hv;
                    *(ushort4*)(vtlbuf + (l + 1) * (NN * DD) + d * NN + m0) = lv;
                }
            } else {
                // classifier GEMMs + S1/S2
                const float* W = Wc1 + (half ? DD * DD : 0);
                float av[4] = {0.f, 0.f, 0.f, 0.f};
#pragma unroll 4
                for (int k4 = 0; k4 < DD; k4 += 4) {
                    f32x4 h0 = *(const f32x4*)&sh.gate.hS[0][k4];
                    f32x4 h1 = *(const f32x4*)&sh.gate.hS[1][k4];
                    f32x4 h2 = *(const f32x4*)&sh.gate.hS[2][k4];
                    f32x4 h3 = *(const f32x4*)&sh.gate.hS[3][k4];
#pragma unroll
                    for (int kk = 0; kk < 4; ++kk) {
                        float w = W[(k4 + kk) * DD + d];
                        av[0] = fmaf(h0[kk], w, av[0]);
                        av[1] = fmaf(h1[kk], w, av[1]);
                        av[2] = fmaf(h2[kk], w, av[2]);
                        av[3] = fmaf(h3[kk], w, av[3]);
                    }
                }
                float wv = Wc2[d];
                float bcv = half ? 0.f : bc1[d];
                float* out = half ? hj : hi;
                int lane = tid & 63;
#pragma unroll
                for (int r = 0; r < 4; ++r) {
                    float val = av[r] + bcv;
                    out[(m0 + r) * DD + d] = val;
                    float p = val * wv;
#pragma unroll
                    for (int off = 32; off; off >>= 1) p += __shfl_down(p, off);
                    if (lane == 0) atomicAdd(&sh.gate.sred[half][r], p);
                }
                __syncthreads();
                if (tid < 4) S1[m0 + tid] = sh.gate.sred[0][tid];
                else if (tid < 8) S2[m0 + tid - 4] = sh.gate.sred[1][tid - 4];
            }
        }
        gridbar(bar, tgt, tid); tgt += 256;
    }

    // ================= edge phase: logits + loss =================
    {
        int i0 = (b >> 4) * 64, j0 = (b & 15) * 64;
        if (tid == 0) sh.edge.lred = 0.f;
        if (tid < 128) sh.edge.wS[tid] = Wc2[tid];
        for (int e = tid; e < 64 * 128; e += 256) {
            int r = e >> 7, hh = e & 127;
            sh.edge.hiT[hh][r] = hi[(i0 + r) * DD + hh];
            sh.edge.hjT[hh][r] = hj[(j0 + r) * DD + hh];
        }
        __syncthreads();
        int tx = tid & 15, ty = tid >> 4;
        float acc[4][4] = {};
#pragma unroll 4
        for (int hh = 0; hh < 128; ++hh) {
            f32x4 a = *(const f32x4*)&sh.edge.hiT[hh][ty * 4];
            f32x4 bb = *(const f32x4*)&sh.edge.hjT[hh][tx * 4];
            float w = sh.edge.wS[hh];
#pragma unroll
            for (int p = 0; p < 4; ++p)
#pragma unroll
                for (int q = 0; q < 4; ++q) {
                    float x = a[p] + bb[q];
                    acc[p][q] = fmaf(fabsf(x), w, acc[p][q]);   // relu via |x|, free modifier
                }
        }
        float bcv = bc2[0];
        float ls = 0.f;
#pragma unroll
        for (int p = 0; p < 4; ++p) {
            int i = i0 + ty * 4 + p;
            float s1 = S1[i];
            int jb = j0 + tx * 4;
            f32x4 s2 = *(const f32x4*)(S2 + jb);
            f32x4 lg;
#pragma unroll
            for (int q = 0; q < 4; ++q)
                lg[q] = fmaf(0.5f, acc[p][q] + s1 + s2[q], bcv);
            *(f32x4*)(outL + (size_t)i * NN + jb) = lg;
            f32x4 a4 = *(const f32x4*)(adj + (size_t)i * NN + jb);
            f32x4 e4 = *(const f32x4*)(ew + (size_t)i * NN + jb);
#pragma unroll
            for (int q = 0; q < 4; ++q) {
                float t = fmaf(lg[q], a4[q], -e4[q]);
                ls = fmaf(t, t, ls);
            }
        }
#pragma unroll
        for (int off = 32; off; off >>= 1) ls += __shfl_down(ls, off);
        if ((tid & 63) == 0) atomicAdd(&sh.edge.lred, ls);
        __syncthreads();
        if (tid == 0) {
            atomicAdd(lossAcc, sh.edge.lred);
            __threadfence();
            unsigned old = atomicAdd(edgeCnt, 1u);
            if (old == 255u) {
                __threadfence();
                outL[(size_t)NN * NN] = (*(volatile float*)lossAcc) * (1.f / (1024.f * 1024.f));
            }
        }
    }
}

extern "C" void kernel_launch(void* const* d_in, const int* in_sizes, int n_in,
                              void* d_out, int out_size, void* d_ws, size_t ws_size,
                              hipStream_t stream)
{
    const float* nf  = (const float*)d_in[0];
    const float* adj = (const float*)d_in[1];
    const float* ew  = (const float*)d_in[2];
    const float* We  = (const float*)d_in[3];
    const float* be  = (const float*)d_in[4];
    const float* Wu  = (const float*)d_in[5];
    const float* bu  = (const float*)d_in[6];
    const float* Wv  = (const float*)d_in[7];
    const float* bv  = (const float*)d_in[8];
    const float* Wg  = (const float*)d_in[9];
    const float* bg  = (const float*)d_in[10];
    const float* Wc1 = (const float*)d_in[11];
    const float* bc1 = (const float*)d_in[12];
    const float* Wc2 = (const float*)d_in[13];
    const float* bc2 = (const float*)d_in[14];

    float* ws = (float*)d_ws;
    float* hbuf   = ws;                                        // 3 x 131072
    float* ubuf   = ws + 393216;                               // 3 x 131072
    float* aggbuf = ws + 786432;                               // 3 x 131072
    unsigned short* vthbuf = (unsigned short*)(ws + 1179648);  // 3 x 131072 bf16
    unsigned short* vtlbuf = (unsigned short*)(ws + 1376256);  // 3 x 131072 bf16
    unsigned short* adjH   = (unsigned short*)(ws + 1572864);  // 1M bf16
    unsigned short* adjL   = (unsigned short*)(ws + 2097152);  // 1M bf16
    float* hi = ws + 2621440;                                  // 131072
    float* hj = ws + 2752512;                                  // 131072
    float* S1 = ws + 2883584;                                  // 1024
    float* S2 = ws + 2884608;                                  // 1024
    unsigned* ctrl = (unsigned*)(ws + 2885632);                // bar, edgeCnt, lossAcc

    hipMemsetAsync(ctrl, 0, 16, stream);
    k_all<<<256, 256, 0, stream>>>(nf, adj, ew, We, be, Wu, bu, Wv, bv, Wg, bg,
                                   Wc1, bc1, Wc2, bc2,
                                   hbuf, ubuf, aggbuf, vthbuf, vtlbuf, adjH, adjL,
                                   hi, hj, S1, S2, ctrl, (float*)d_out);
}

// Round 5
// 240.308 us; speedup vs baseline: 1.4325x; 1.4325x over previous
//
#include <hip/hip_runtime.h>

#define NN 1024
#define DD 128

typedef __attribute__((ext_vector_type(4))) float f32x4;

// ---------------- kernel 1: embed + u/v layer-0 GEMMs (4 rows/block) ----------------
__global__ __launch_bounds__(256) void k_embuv(
    const float* __restrict__ nf, const float* __restrict__ We, const float* __restrict__ be,
    const float* __restrict__ Wu, const float* __restrict__ bu,
    const float* __restrict__ Wv, const float* __restrict__ bv,
    float* __restrict__ h, float* __restrict__ u, float* __restrict__ v,
    unsigned* __restrict__ ctrl)
{
    __shared__ float hS[4][DD];
    int b = blockIdx.x, tid = threadIdx.x;
    if (b == 0 && tid < 4) ctrl[tid] = 0u;          // bar/cnt/lossAcc zero, every launch
    int m0 = b * 4;
    int d = tid & 127, half = tid >> 7;
    if (half == 0) {
#pragma unroll
        for (int r = 0; r < 4; ++r) {
            float a = be[d];
#pragma unroll
            for (int k = 0; k < 3; ++k) a = fmaf(nf[(m0 + r) * 3 + k], We[k * DD + d], a);
            h[(m0 + r) * DD + d] = a;
            hS[r][d] = a;
        }
    }
    __syncthreads();
    const float* W = half ? Wv : Wu;
    float acc[4] = {0.f, 0.f, 0.f, 0.f};
#pragma unroll 4
    for (int k4 = 0; k4 < DD; k4 += 4) {
        f32x4 h0 = *(const f32x4*)&hS[0][k4];
        f32x4 h1 = *(const f32x4*)&hS[1][k4];
        f32x4 h2 = *(const f32x4*)&hS[2][k4];
        f32x4 h3 = *(const f32x4*)&hS[3][k4];
#pragma unroll
        for (int kk = 0; kk < 4; ++kk) {
            float w = W[(k4 + kk) * DD + d];
            acc[0] = fmaf(h0[kk], w, acc[0]);
            acc[1] = fmaf(h1[kk], w, acc[1]);
            acc[2] = fmaf(h2[kk], w, acc[2]);
            acc[3] = fmaf(h3[kk], w, acc[3]);
        }
    }
    if (half == 0) {
        float bb = bu[d];
#pragma unroll
        for (int r = 0; r < 4; ++r) u[(m0 + r) * DD + d] = acc[r] + bb;
    } else {
        float bb = bv[d];
#pragma unroll
        for (int r = 0; r < 4; ++r) v[(m0 + r) * DD + d] = acc[r] + bb;
    }
}

// ---- shared LDS layout for the fused layer kernels ----
struct LSh {
    float aggS[4][DD];
    float uS[4][DD];
    float hS[4][DD];
    float sred[2][4];
};

// agg rows m0..m0+3 = adj rows @ v ; one wave per row, adj via scalar loads.
__device__ __forceinline__ void agg_phase(
    const float* __restrict__ adj, const float* __restrict__ vcur,
    int m0, int tid, LSh* sh)
{
    int w = __builtin_amdgcn_readfirstlane(tid >> 6);   // wave index -> row (wave-uniform)
    int c2 = (tid & 63) * 2;
    const float* arow = adj + (size_t)(m0 + w) * NN;    // scalar pointer -> s_load
    float ax = 0.f, ay = 0.f;
#pragma unroll 8
    for (int k4 = 0; k4 < NN; k4 += 4) {
        f32x4 a4 = *(const f32x4*)(arow + k4);          // SMEM dwordx4
#pragma unroll
        for (int kk = 0; kk < 4; ++kk) {
            float2 v2 = *(const float2*)(vcur + (k4 + kk) * DD + c2);
            ax = fmaf(a4[kk], v2.x, ax);
            ay = fmaf(a4[kk], v2.y, ay);
        }
    }
    *(float2*)&sh->aggS[w][c2] = make_float2(ax, ay);
    __syncthreads();
}

// gate GEMM + h update; result left in sh->hS (and optionally written to h).
__device__ __forceinline__ void gate_phase(
    const float* __restrict__ u, float* __restrict__ h,
    const float* __restrict__ Wg, const float* __restrict__ bg,
    int m0, int tid, int d, int half, LSh* sh)
{
#pragma unroll
    for (int e = tid; e < 512; e += 256) {
        int r = e >> 7, dd = e & 127;
        sh->uS[r][dd] = u[(m0 + r) * DD + dd];
    }
    __syncthreads();
    const float* WA = Wg;
    const float* WB = Wg + DD * DD;
    int r0 = half * 2;
    float acc[2] = {0.f, 0.f};
#pragma unroll 4
    for (int k4 = 0; k4 < DD; k4 += 4) {
        f32x4 u0 = *(const f32x4*)&sh->uS[r0][k4];
        f32x4 u1 = *(const f32x4*)&sh->uS[r0 + 1][k4];
        f32x4 a0 = *(const f32x4*)&sh->aggS[r0][k4];
        f32x4 a1 = *(const f32x4*)&sh->aggS[r0 + 1][k4];
#pragma unroll
        for (int kk = 0; kk < 4; ++kk) {
            float wa = WA[(k4 + kk) * DD + d];
            float wb = WB[(k4 + kk) * DD + d];
            acc[0] = fmaf(u0[kk], wa, fmaf(a0[kk], wb, acc[0]));
            acc[1] = fmaf(u1[kk], wa, fmaf(a1[kk], wb, acc[1]));
        }
    }
    float bgd = bg[d];
#pragma unroll
    for (int rr = 0; rr < 2; ++rr) {
        int r = r0 + rr;
        float g = 1.f / (1.f + __expf(-(acc[rr] + bgd)));
        float nh = fmaf(g, sh->aggS[r][d], h[(m0 + r) * DD + d]);
        nh = nh > 0.f ? nh : 0.f;
        sh->hS[r][d] = nh;
        h[(m0 + r) * DD + d] = nh;
    }
    __syncthreads();
}

// ---------------- fused layer kernel (layers 0,1): agg+gate+h + next u/v ----------------
__global__ __launch_bounds__(256) void k_layer(
    const float* __restrict__ adj, const float* __restrict__ vcur,
    float* __restrict__ u, float* __restrict__ h,
    const float* __restrict__ Wg, const float* __restrict__ bg,
    const float* __restrict__ Wun, const float* __restrict__ bun,
    const float* __restrict__ Wvn, const float* __restrict__ bvn,
    float* __restrict__ vnext)
{
    __shared__ LSh sh;
    int b = blockIdx.x, tid = threadIdx.x;
    int m0 = b * 4;
    int d = tid & 127, half = tid >> 7;
    agg_phase(adj, vcur, m0, tid, &sh);
    gate_phase(u, h, Wg, bg, m0, tid, d, half, &sh);
    const float* W = half ? Wvn : Wun;
    float av[4] = {0.f, 0.f, 0.f, 0.f};
#pragma unroll 4
    for (int k4 = 0; k4 < DD; k4 += 4) {
        f32x4 h0 = *(const f32x4*)&sh.hS[0][k4];
        f32x4 h1 = *(const f32x4*)&sh.hS[1][k4];
        f32x4 h2 = *(const f32x4*)&sh.hS[2][k4];
        f32x4 h3 = *(const f32x4*)&sh.hS[3][k4];
#pragma unroll
        for (int kk = 0; kk < 4; ++kk) {
            float w = W[(k4 + kk) * DD + d];
            av[0] = fmaf(h0[kk], w, av[0]);
            av[1] = fmaf(h1[kk], w, av[1]);
            av[2] = fmaf(h2[kk], w, av[2]);
            av[3] = fmaf(h3[kk], w, av[3]);
        }
    }
    float bb = half ? bvn[d] : bun[d];
    float* out = half ? vnext : u;
#pragma unroll
    for (int r = 0; r < 4; ++r) out[(m0 + r) * DD + d] = av[r] + bb;
}

// ---------------- fused layer kernel (layer 2): agg+gate+h + classifier + S1/S2 ----------------
__global__ __launch_bounds__(256) void k_layercls(
    const float* __restrict__ adj, const float* __restrict__ vcur,
    float* __restrict__ u, float* __restrict__ h,
    const float* __restrict__ Wg, const float* __restrict__ bg,
    const float* __restrict__ Wc1, const float* __restrict__ bc1, const float* __restrict__ Wc2,
    float* __restrict__ hi, float* __restrict__ hj,
    float* __restrict__ S1, float* __restrict__ S2)
{
    __shared__ LSh sh;
    int b = blockIdx.x, tid = threadIdx.x;
    int m0 = b * 4;
    int d = tid & 127, half = tid >> 7;
    if (tid < 8) sh.sred[tid >> 2][tid & 3] = 0.f;
    agg_phase(adj, vcur, m0, tid, &sh);
    gate_phase(u, h, Wg, bg, m0, tid, d, half, &sh);
    const float* W = Wc1 + (half ? DD * DD : 0);
    float av[4] = {0.f, 0.f, 0.f, 0.f};
#pragma unroll 4
    for (int k4 = 0; k4 < DD; k4 += 4) {
        f32x4 h0 = *(const f32x4*)&sh.hS[0][k4];
        f32x4 h1 = *(const f32x4*)&sh.hS[1][k4];
        f32x4 h2 = *(const f32x4*)&sh.hS[2][k4];
        f32x4 h3 = *(const f32x4*)&sh.hS[3][k4];
#pragma unroll
        for (int kk = 0; kk < 4; ++kk) {
            float w = W[(k4 + kk) * DD + d];
            av[0] = fmaf(h0[kk], w, av[0]);
            av[1] = fmaf(h1[kk], w, av[1]);
            av[2] = fmaf(h2[kk], w, av[2]);
            av[3] = fmaf(h3[kk], w, av[3]);
        }
    }
    float wv = Wc2[d];
    float bcv = half ? 0.f : bc1[d];
    float* out = half ? hj : hi;
    int lane = tid & 63;
#pragma unroll
    for (int r = 0; r < 4; ++r) {
        float val = av[r] + bcv;
        out[(m0 + r) * DD + d] = val;
        float p = val * wv;
#pragma unroll
        for (int off = 32; off; off >>= 1) p += __shfl_down(p, off);
        if (lane == 0) atomicAdd(&sh.sred[half][r], p);
    }
    __syncthreads();
    if (tid < 4) S1[m0 + tid] = sh.sred[0][tid];
    else if (tid < 8) S2[m0 + tid - 4] = sh.sred[1][tid - 4];
}

// ---------------- logits + loss; relu(x)=(x+|x|)/2 trick; last block finalizes loss ----------------
__global__ __launch_bounds__(256) void k_edge(
    const float* __restrict__ hi, const float* __restrict__ hj,
    const float* __restrict__ S1, const float* __restrict__ S2,
    const float* __restrict__ Wc2, const float* __restrict__ bc2,
    const float* __restrict__ adj, const float* __restrict__ ew,
    float* __restrict__ outL, unsigned* __restrict__ ctrl)
{
    __shared__ float hiT[128][68];   // stride 68 keeps float4 rows 16B-aligned
    __shared__ float hjT[128][68];
    __shared__ float wS[128];
    __shared__ float lred;
    int tid = threadIdx.x;
    int i0 = (blockIdx.x >> 4) * 64, j0 = (blockIdx.x & 15) * 64;
    if (tid == 0) lred = 0.f;
    if (tid < 128) wS[tid] = Wc2[tid];
    for (int e = tid; e < 64 * 128; e += 256) {
        int r = e >> 7, hh = e & 127;
        hiT[hh][r] = hi[(i0 + r) * DD + hh];
        hjT[hh][r] = hj[(j0 + r) * DD + hh];
    }
    __syncthreads();
    int tx = tid & 15, ty = tid >> 4;
    float acc[4][4] = {};
#pragma unroll 4
    for (int hh = 0; hh < 128; ++hh) {
        f32x4 a = *(const f32x4*)&hiT[hh][ty * 4];
        f32x4 bb = *(const f32x4*)&hjT[hh][tx * 4];
        float w = wS[hh];
#pragma unroll
        for (int p = 0; p < 4; ++p)
#pragma unroll
            for (int q = 0; q < 4; ++q) {
                float x = a[p] + bb[q];
                acc[p][q] = fmaf(fabsf(x), w, acc[p][q]);   // |x| is a free modifier
            }
    }
    float bcv = bc2[0];
    float ls = 0.f;
#pragma unroll
    for (int p = 0; p < 4; ++p) {
        int i = i0 + ty * 4 + p;
        float s1 = S1[i];
        int jb = j0 + tx * 4;
        f32x4 s2 = *(const f32x4*)(S2 + jb);
        f32x4 lg;
#pragma unroll
        for (int q = 0; q < 4; ++q)
            lg[q] = fmaf(0.5f, acc[p][q] + s1 + s2[q], bcv);
        *(f32x4*)(outL + (size_t)i * NN + jb) = lg;
        f32x4 a4 = *(const f32x4*)(adj + (size_t)i * NN + jb);
        f32x4 e4 = *(const f32x4*)(ew + (size_t)i * NN + jb);
#pragma unroll
        for (int q = 0; q < 4; ++q) {
            float t = fmaf(lg[q], a4[q], -e4[q]);
            ls = fmaf(t, t, ls);
        }
    }
#pragma unroll
    for (int off = 32; off; off >>= 1) ls += __shfl_down(ls, off);
    if ((tid & 63) == 0) atomicAdd(&lred, ls);
    __syncthreads();
    if (tid == 0) {
        float* lossAcc = (float*)(ctrl + 2);
        atomicAdd(lossAcc, lred);
        __threadfence();
        unsigned old = atomicAdd(ctrl + 1, 1u);
        if (old == 255u) {
            __threadfence();
            outL[(size_t)NN * NN] = (*(volatile float*)lossAcc) * (1.f / (1024.f * 1024.f));
        }
    }
}

extern "C" void kernel_launch(void* const* d_in, const int* in_sizes, int n_in,
                              void* d_out, int out_size, void* d_ws, size_t ws_size,
                              hipStream_t stream)
{
    const float* nf  = (const float*)d_in[0];
    const float* adj = (const float*)d_in[1];
    const float* ew  = (const float*)d_in[2];
    const float* We  = (const float*)d_in[3];
    const float* be  = (const float*)d_in[4];
    const float* Wu  = (const float*)d_in[5];
    const float* bu  = (const float*)d_in[6];
    const float* Wv  = (const float*)d_in[7];
    const float* bv  = (const float*)d_in[8];
    const float* Wg  = (const float*)d_in[9];
    const float* bg  = (const float*)d_in[10];
    const float* Wc1 = (const float*)d_in[11];
    const float* bc1 = (const float*)d_in[12];
    const float* Wc2 = (const float*)d_in[13];
    const float* bc2 = (const float*)d_in[14];

    float* ws = (float*)d_ws;
    float* h   = ws;                       // 131072
    float* u   = ws + 131072;              // 131072
    float* v0  = ws + 262144;              // 131072 (v ping)
    float* v1  = ws + 393216;              // 131072 (v pong)
    float* hi  = ws + 524288;              // 131072
    float* hj  = ws + 655360;              // 131072
    float* S1  = ws + 786432;              // 1024
    float* S2  = ws + 787456;              // 1024
    unsigned* ctrl = (unsigned*)(ws + 788480);   // [bar, edgeCnt, lossAcc, pad]

    k_embuv<<<256, 256, 0, stream>>>(nf, We, be, Wu, bu, Wv, bv, h, u, v0, ctrl);
    k_layer<<<256, 256, 0, stream>>>(adj, v0, u, h, Wg, bg,
                                     Wu + 16384, bu + 128, Wv + 16384, bv + 128, v1);
    k_layer<<<256, 256, 0, stream>>>(adj, v1, u, h, Wg + 32768, bg + 128,
                                     Wu + 32768, bu + 256, Wv + 32768, bv + 256, v0);
    k_layercls<<<256, 256, 0, stream>>>(adj, v0, u, h, Wg + 65536, bg + 256,
                                        Wc1, bc1, Wc2, hi, hj, S1, S2);
    k_edge<<<256, 256, 0, stream>>>(hi, hj, S1, S2, Wc2, bc2, adj, ew,
                                    (float*)d_out, ctrl);
}

// Round 6
// 190.711 us; speedup vs baseline: 1.8050x; 1.2601x over previous
//
#include <hip/hip_runtime.h>

#define NN 1024
#define DD 128

typedef __attribute__((ext_vector_type(4))) float f32x4;

// ---------------- K1: embed + u0/v0 GEMMs (2 rows/block, 512 blocks) ----------------
__global__ __launch_bounds__(256) void k_embuv(
    const float* __restrict__ nf, const float* __restrict__ We, const float* __restrict__ be,
    const float* __restrict__ Wu, const float* __restrict__ bu,
    const float* __restrict__ Wv, const float* __restrict__ bv,
    float* __restrict__ h, float* __restrict__ u, float* __restrict__ v,
    unsigned* __restrict__ ctrl)
{
    __shared__ float hS[2][DD];
    int b = blockIdx.x, tid = threadIdx.x;
    if (b == 0 && tid < 4) ctrl[tid] = 0u;          // counter/lossAcc zero, every launch
    int m0 = b * 2, d = tid & 127, half = tid >> 7;
    if (half == 0) {
#pragma unroll
        for (int r = 0; r < 2; ++r) {
            float a = be[d];
#pragma unroll
            for (int k = 0; k < 3; ++k) a = fmaf(nf[(m0 + r) * 3 + k], We[k * DD + d], a);
            h[(m0 + r) * DD + d] = a;
            hS[r][d] = a;
        }
    }
    __syncthreads();
    const float* W = half ? Wv : Wu;
    float a0 = 0.f, a1 = 0.f;
#pragma unroll 4
    for (int k4 = 0; k4 < DD; k4 += 4) {
        f32x4 h0 = *(const f32x4*)&hS[0][k4];
        f32x4 h1 = *(const f32x4*)&hS[1][k4];
#pragma unroll
        for (int kk = 0; kk < 4; ++kk) {
            float w = W[(k4 + kk) * DD + d];
            a0 = fmaf(h0[kk], w, a0);
            a1 = fmaf(h1[kk], w, a1);
        }
    }
    float bb = half ? bv[d] : bu[d];
    float* out = half ? v : u;
    out[m0 * DD + d] = a0 + bb;
    out[(m0 + 1) * DD + d] = a1 + bb;
}

// ---------------- K2: agg partials. 1024 blocks = 128 rowgroups(8 rows) x 8 k-chunks ----------------
// adj values via wave-uniform scalar loads; v via coalesced float2; 4-wave LDS reduce -> P[kc].
__global__ __launch_bounds__(256) void k_agg(
    const float* __restrict__ adj, const float* __restrict__ v, float* __restrict__ P)
{
    __shared__ float red[4][64][17];   // +1 pad breaks 16-float stride conflicts
    int tid = threadIdx.x, b = blockIdx.x;
    int rg = b >> 3, kc = b & 7;
    int m0 = rg * 8;
    int w = tid >> 6, l = tid & 63;
    int kbase = kc * 128 + w * 32;
    int c2 = l * 2;
    float acc[8][2] = {};
    const float* vp = v + (size_t)kbase * DD + c2;
#pragma unroll
    for (int kk4 = 0; kk4 < 32; kk4 += 4) {
        f32x4 a[8];
#pragma unroll
        for (int r = 0; r < 8; ++r)
            a[r] = *(const f32x4*)(adj + (size_t)(m0 + r) * NN + kbase + kk4);   // uniform -> s_load
#pragma unroll
        for (int kk = 0; kk < 4; ++kk) {
            float2 v2 = *(const float2*)(vp + (kk4 + kk) * DD);
#pragma unroll
            for (int r = 0; r < 8; ++r) {
                acc[r][0] = fmaf(a[r][kk], v2.x, acc[r][0]);
                acc[r][1] = fmaf(a[r][kk], v2.y, acc[r][1]);
            }
        }
    }
#pragma unroll
    for (int r = 0; r < 8; ++r) {
        red[w][l][r * 2] = acc[r][0];
        red[w][l][r * 2 + 1] = acc[r][1];
    }
    __syncthreads();
    float* Pk = P + (size_t)kc * (NN * DD);
#pragma unroll
    for (int rr = 0; rr < 2; ++rr) {
        int r = w * 2 + rr;
        float s0 = 0.f, s1 = 0.f;
#pragma unroll
        for (int ww = 0; ww < 4; ++ww) {
            s0 += red[ww][l][r * 2];
            s1 += red[ww][l][r * 2 + 1];
        }
        *(float2*)(Pk + (size_t)(m0 + r) * DD + c2) = make_float2(s0, s1);
    }
}

// ---------------- K3: sum P + gate (A/B split across halves) + h update + next u/v ----------------
__global__ __launch_bounds__(256) void k_gateuv(
    const float* __restrict__ P, float* __restrict__ u, float* __restrict__ h,
    const float* __restrict__ Wg, const float* __restrict__ bg,
    const float* __restrict__ Wun, const float* __restrict__ bun,
    const float* __restrict__ Wvn, const float* __restrict__ bvn,
    float* __restrict__ vnext)
{
    __shared__ float aggS[2][DD], uS[2][DD], gpart[2][2][DD], hS[2][DD];
    int tid = threadIdx.x, b = blockIdx.x;
    int m0 = b * 2, d = tid & 127, half = tid >> 7;
    {
        int r = half, dd = d;
        int idx = (m0 + r) * DD + dd;
        float s = 0.f;
#pragma unroll
        for (int c = 0; c < 8; ++c) s += P[(size_t)c * (NN * DD) + idx];
        aggS[r][dd] = s;
        uS[r][dd] = u[idx];
    }
    __syncthreads();
    {   // gate partial: half0 = u@WA, half1 = agg@WB
        const float* W = Wg + (half ? DD * DD : 0);
        const float(*X)[DD] = half ? aggS : uS;
        float g0 = 0.f, g1 = 0.f;
#pragma unroll 4
        for (int k4 = 0; k4 < DD; k4 += 4) {
            f32x4 x0 = *(const f32x4*)&X[0][k4];
            f32x4 x1 = *(const f32x4*)&X[1][k4];
#pragma unroll
            for (int kk = 0; kk < 4; ++kk) {
                float w = W[(k4 + kk) * DD + d];
                g0 = fmaf(x0[kk], w, g0);
                g1 = fmaf(x1[kk], w, g1);
            }
        }
        gpart[half][0][d] = g0;
        gpart[half][1][d] = g1;
    }
    __syncthreads();
    {
        int r = half, dd = d;
        float z = gpart[0][r][dd] + gpart[1][r][dd] + bg[dd];
        float g = 1.f / (1.f + __expf(-z));
        float nh = fmaf(g, aggS[r][dd], h[(m0 + r) * DD + dd]);
        nh = nh > 0.f ? nh : 0.f;
        h[(m0 + r) * DD + dd] = nh;
        hS[r][dd] = nh;
    }
    __syncthreads();
    const float* W2 = half ? Wvn : Wun;
    float a0 = 0.f, a1 = 0.f;
#pragma unroll 4
    for (int k4 = 0; k4 < DD; k4 += 4) {
        f32x4 h0 = *(const f32x4*)&hS[0][k4];
        f32x4 h1 = *(const f32x4*)&hS[1][k4];
#pragma unroll
        for (int kk = 0; kk < 4; ++kk) {
            float w = W2[(k4 + kk) * DD + d];
            a0 = fmaf(h0[kk], w, a0);
            a1 = fmaf(h1[kk], w, a1);
        }
    }
    float bb = half ? bvn[d] : bun[d];
    float* out = half ? vnext : u;
    out[m0 * DD + d] = a0 + bb;
    out[(m0 + 1) * DD + d] = a1 + bb;
}

// ---------------- K4: sum P + gate + h + classifier (hi/hj) + S1/S2 ----------------
__global__ __launch_bounds__(256) void k_gatecls(
    const float* __restrict__ P, float* __restrict__ u, float* __restrict__ h,
    const float* __restrict__ Wg, const float* __restrict__ bg,
    const float* __restrict__ Wc1, const float* __restrict__ bc1, const float* __restrict__ Wc2,
    float* __restrict__ hi, float* __restrict__ hj,
    float* __restrict__ S1, float* __restrict__ S2)
{
    __shared__ float aggS[2][DD], uS[2][DD], gpart[2][2][DD], hS[2][DD];
    __shared__ float sred[2][2];
    int tid = threadIdx.x, b = blockIdx.x;
    int m0 = b * 2, d = tid & 127, half = tid >> 7;
    if (tid < 4) sred[tid >> 1][tid & 1] = 0.f;
    {
        int idx = (m0 + half) * DD + d;
        float s = 0.f;
#pragma unroll
        for (int c = 0; c < 8; ++c) s += P[(size_t)c * (NN * DD) + idx];
        aggS[half][d] = s;
        uS[half][d] = u[idx];
    }
    __syncthreads();
    {
        const float* W = Wg + (half ? DD * DD : 0);
        const float(*X)[DD] = half ? aggS : uS;
        float g0 = 0.f, g1 = 0.f;
#pragma unroll 4
        for (int k4 = 0; k4 < DD; k4 += 4) {
            f32x4 x0 = *(const f32x4*)&X[0][k4];
            f32x4 x1 = *(const f32x4*)&X[1][k4];
#pragma unroll
            for (int kk = 0; kk < 4; ++kk) {
                float w = W[(k4 + kk) * DD + d];
                g0 = fmaf(x0[kk], w, g0);
                g1 = fmaf(x1[kk], w, g1);
            }
        }
        gpart[half][0][d] = g0;
        gpart[half][1][d] = g1;
    }
    __syncthreads();
    {
        float z = gpart[0][half][d] + gpart[1][half][d] + bg[d];
        float g = 1.f / (1.f + __expf(-z));
        float nh = fmaf(g, aggS[half][d], h[(m0 + half) * DD + d]);
        nh = nh > 0.f ? nh : 0.f;
        hS[half][d] = nh;
    }
    __syncthreads();
    const float* W2 = Wc1 + (half ? DD * DD : 0);
    float a0 = 0.f, a1 = 0.f;
#pragma unroll 4
    for (int k4 = 0; k4 < DD; k4 += 4) {
        f32x4 h0 = *(const f32x4*)&hS[0][k4];
        f32x4 h1 = *(const f32x4*)&hS[1][k4];
#pragma unroll
        for (int kk = 0; kk < 4; ++kk) {
            float w = W2[(k4 + kk) * DD + d];
            a0 = fmaf(h0[kk], w, a0);
            a1 = fmaf(h1[kk], w, a1);
        }
    }
    float wv = Wc2[d];
    float bcv = half ? 0.f : bc1[d];
    float* out = half ? hj : hi;
#pragma unroll
    for (int r = 0; r < 2; ++r) {
        float val = (r ? a1 : a0) + bcv;
        out[(m0 + r) * DD + d] = val;
        float p = val * wv;
#pragma unroll
        for (int off = 32; off; off >>= 1) p += __shfl_down(p, off);
        if ((tid & 63) == 0) atomicAdd(&sred[half][r], p);
    }
    __syncthreads();
    if (tid < 2) S1[m0 + tid] = sred[0][tid];
    else if (tid < 4) S2[m0 + tid - 2] = sred[1][tid - 2];
}

// ---------------- K5: logits + loss; 64x64 tiles, 4x4 micro; relu via |x| modifier ----------------
__global__ __launch_bounds__(256) void k_edge(
    const float* __restrict__ hi, const float* __restrict__ hj,
    const float* __restrict__ S1, const float* __restrict__ S2,
    const float* __restrict__ Wc2, const float* __restrict__ bc2,
    const float* __restrict__ adj, const float* __restrict__ ew,
    float* __restrict__ outL, unsigned* __restrict__ ctrl)
{
    __shared__ float hiT[128][68];   // stride 68 keeps float4 rows 16B-aligned
    __shared__ float hjT[128][68];
    __shared__ float lred;
    int tid = threadIdx.x;
    int i0 = (blockIdx.x >> 4) * 64, j0 = (blockIdx.x & 15) * 64;
    if (tid == 0) lred = 0.f;
    for (int e = tid; e < 64 * 128; e += 256) {
        int r = e >> 7, hh = e & 127;
        hiT[hh][r] = hi[(i0 + r) * DD + hh];
        hjT[hh][r] = hj[(j0 + r) * DD + hh];
    }
    __syncthreads();
    int tx = tid & 15, ty = tid >> 4;
    float acc[4][4] = {};
#pragma unroll 4
    for (int hh = 0; hh < 128; ++hh) {
        f32x4 a = *(const f32x4*)&hiT[hh][ty * 4];
        f32x4 bb = *(const f32x4*)&hjT[hh][tx * 4];
        float w = Wc2[hh];                       // wave-uniform -> s_load, K$-cached
#pragma unroll
        for (int p = 0; p < 4; ++p)
#pragma unroll
            for (int q = 0; q < 4; ++q) {
                float x = a[p] + bb[q];
                acc[p][q] = fmaf(fabsf(x), w, acc[p][q]);
            }
    }
    float bcv = bc2[0];
    float ls = 0.f;
#pragma unroll
    for (int p = 0; p < 4; ++p) {
        int i = i0 + ty * 4 + p;
        float s1 = S1[i];
        int jb = j0 + tx * 4;
        f32x4 s2 = *(const f32x4*)(S2 + jb);
        f32x4 lg;
#pragma unroll
        for (int q = 0; q < 4; ++q)
            lg[q] = fmaf(0.5f, acc[p][q] + s1 + s2[q], bcv);
        *(f32x4*)(outL + (size_t)i * NN + jb) = lg;
        f32x4 a4 = *(const f32x4*)(adj + (size_t)i * NN + jb);
        f32x4 e4 = *(const f32x4*)(ew + (size_t)i * NN + jb);
#pragma unroll
        for (int q = 0; q < 4; ++q) {
            float t = fmaf(lg[q], a4[q], -e4[q]);
            ls = fmaf(t, t, ls);
        }
    }
#pragma unroll
    for (int off = 32; off; off >>= 1) ls += __shfl_down(ls, off);
    if ((tid & 63) == 0) atomicAdd(&lred, ls);
    __syncthreads();
    if (tid == 0) {
        float* lossAcc = (float*)(ctrl + 2);
        atomicAdd(lossAcc, lred);
        __threadfence();
        unsigned old = atomicAdd(ctrl + 1, 1u);
        if (old == 255u) {
            __threadfence();
            outL[(size_t)NN * NN] = (*(volatile float*)lossAcc) * (1.f / (1024.f * 1024.f));
        }
    }
}

extern "C" void kernel_launch(void* const* d_in, const int* in_sizes, int n_in,
                              void* d_out, int out_size, void* d_ws, size_t ws_size,
                              hipStream_t stream)
{
    const float* nf  = (const float*)d_in[0];
    const float* adj = (const float*)d_in[1];
    const float* ew  = (const float*)d_in[2];
    const float* We  = (const float*)d_in[3];
    const float* be  = (const float*)d_in[4];
    const float* Wu  = (const float*)d_in[5];
    const float* bu  = (const float*)d_in[6];
    const float* Wv  = (const float*)d_in[7];
    const float* bv  = (const float*)d_in[8];
    const float* Wg  = (const float*)d_in[9];
    const float* bg  = (const float*)d_in[10];
    const float* Wc1 = (const float*)d_in[11];
    const float* bc1 = (const float*)d_in[12];
    const float* Wc2 = (const float*)d_in[13];
    const float* bc2 = (const float*)d_in[14];

    float* ws = (float*)d_ws;
    float* h   = ws;                       // 131072
    float* u   = ws + 131072;              // 131072
    float* v0  = ws + 262144;              // 131072 (v ping)
    float* v1  = ws + 393216;              // 131072 (v pong)
    float* hi  = ws + 524288;              // 131072
    float* hj  = ws + 655360;              // 131072
    float* P   = ws + 786432;              // 8 x 131072 partials
    float* S1  = ws + 1835008;             // 1024
    float* S2  = ws + 1836032;             // 1024
    unsigned* ctrl = (unsigned*)(ws + 1837056);   // [pad, edgeCnt, lossAcc, pad]

    k_embuv<<<512, 256, 0, stream>>>(nf, We, be, Wu, bu, Wv, bv, h, u, v0, ctrl);
    k_agg<<<1024, 256, 0, stream>>>(adj, v0, P);
    k_gateuv<<<512, 256, 0, stream>>>(P, u, h, Wg, bg,
                                      Wu + 16384, bu + 128, Wv + 16384, bv + 128, v1);
    k_agg<<<1024, 256, 0, stream>>>(adj, v1, P);
    k_gateuv<<<512, 256, 0, stream>>>(P, u, h, Wg + 32768, bg + 128,
                                      Wu + 32768, bu + 256, Wv + 32768, bv + 256, v0);
    k_agg<<<1024, 256, 0, stream>>>(adj, v0, P);
    k_gatecls<<<512, 256, 0, stream>>>(P, u, h, Wg + 65536, bg + 256,
                                       Wc1, bc1, Wc2, hi, hj, S1, S2);
    k_edge<<<256, 256, 0, stream>>>(hi, hj, S1, S2, Wc2, bc2, adj, ew,
                                    (float*)d_out, ctrl);
}